// Round 2
// baseline (376.178 us; speedup 1.0000x reference)
//
#include <hip/hip_runtime.h>
#include <math.h>

// MS-SSIM on (16,1,512,512) fp32, 5 levels, 11x11 gaussian (sigma=1.5), 2x2 avg-pool.
// Round-1 structure: 64x64 tile per block, 256 threads, each thread computes a
// 4-wide x 4-tall output patch. Horizontal conv is computed on the fly from the
// staged LDS tile (aligned ds_read_b128 sliding window); vertical conv
// accumulates in 80 registers (5 planes x 4 rows x 4 cols). No h-plane LDS
// round-trip. Pooling fused. Per-block partials -> tiny finalize kernel.

#define WS 11
#define TW 64          // output tile width
#define TH 64          // output tile height
#define SROWS 74       // TH + 10 (vertical halo 5+5)
#define SCOLS 80       // staged cols: x0-8 .. x0+71 (left halo padded to 8 for alignment)
#define SSTRIDE 84     // padded LDS row stride in floats (16B-aligned, bank spread)

__global__ __launch_bounds__(256, 3) void ssim_level_kernel(
    const float* __restrict__ img1, const float* __restrict__ img2,
    int H, int W,
    float* __restrict__ pool1, float* __restrict__ pool2,  // null on last level
    float* __restrict__ partials)                           // 2 floats per block
{
    __shared__ float s1[SROWS * SSTRIDE];
    __shared__ float s2[SROWS * SSTRIDE];
    __shared__ float wg[WS];
    __shared__ float red[2][4];

    const int tid = threadIdx.x;

    // Gaussian window in double, normalized, cast to f32 (matches reference).
    if (tid == 0) {
        double gbuf[WS];
        double s = 0.0;
        for (int i = 0; i < WS; ++i) {
            double d = (double)(i - WS / 2);
            gbuf[i] = exp(-(d * d) / (2.0 * 1.5 * 1.5));
            s += gbuf[i];
        }
        for (int i = 0; i < WS; ++i) wg[i] = (float)(gbuf[i] / s);
    }

    const int bx = blockIdx.x, by = blockIdx.y, b = blockIdx.z;
    const int x0 = bx * TW, y0 = by * TH;
    const float* p1 = img1 + (size_t)b * H * W;
    const float* p2 = img2 + (size_t)b * H * W;

    // ---- Stage: rows y0-5..y0+68 (74), cols x0-8..x0+71 (80), zero-padded OOB.
    // float4 global loads (16B-aligned: x0 multiple of 64, offset -8+4*c4 => mult of 4).
    for (int idx = tid; idx < SROWS * (SCOLS / 4); idx += 256) {
        int r = idx / (SCOLS / 4);
        int c4 = idx - r * (SCOLS / 4);
        int gy = y0 - 5 + r;
        int gx = x0 - 8 + 4 * c4;
        float4 v1 = make_float4(0.f, 0.f, 0.f, 0.f);
        float4 v2 = make_float4(0.f, 0.f, 0.f, 0.f);
        if (gy >= 0 && gy < H) {
            const float* r1p = p1 + (size_t)gy * W;
            const float* r2p = p2 + (size_t)gy * W;
            if (gx >= 0 && gx + 3 < W) {
                v1 = *(const float4*)(r1p + gx);
                v2 = *(const float4*)(r2p + gx);
            } else {
                float a1[4] = {0.f, 0.f, 0.f, 0.f};
                float a2[4] = {0.f, 0.f, 0.f, 0.f};
#pragma unroll
                for (int u = 0; u < 4; ++u) {
                    int gxx = gx + u;
                    if (gxx >= 0 && gxx < W) { a1[u] = r1p[gxx]; a2[u] = r2p[gxx]; }
                }
                v1 = make_float4(a1[0], a1[1], a1[2], a1[3]);
                v2 = make_float4(a2[0], a2[1], a2[2], a2[3]);
            }
        }
        *(float4*)&s1[r * SSTRIDE + 4 * c4] = v1;
        *(float4*)&s2[r * SSTRIDE + 4 * c4] = v2;
    }
    __syncthreads();

    // Horizontal weights into registers (LDS broadcast once).
    float w[WS];
#pragma unroll
    for (int j = 0; j < WS; ++j) w[j] = wg[j];

    const int x = tid & 15;   // strip: output cols 4x..4x+3
    const int g = tid >> 4;   // row group: output rows 4g..4g+3

    // ---- Fused 2x2 avg-pool for the next level (from staged LDS tile).
    if (pool1 != nullptr) {
        int Hp = H >> 1, Wp = W >> 1;
#pragma unroll
        for (int pr = 0; pr < 2; ++pr) {
            int sr = 4 * g + 2 * pr + 5;   // s row of top of 2x2 window
            int sc = 4 * x + 8;            // s col (global x0 + 4x)
            float4 a0 = *(const float4*)&s1[sr * SSTRIDE + sc];
            float4 a1 = *(const float4*)&s1[(sr + 1) * SSTRIDE + sc];
            float4 b0 = *(const float4*)&s2[sr * SSTRIDE + sc];
            float4 b1 = *(const float4*)&s2[(sr + 1) * SSTRIDE + sc];
            float pA0 = 0.25f * (a0.x + a0.y + a1.x + a1.y);
            float pA1 = 0.25f * (a0.z + a0.w + a1.z + a1.w);
            float pB0 = 0.25f * (b0.x + b0.y + b1.x + b1.y);
            float pB1 = 0.25f * (b0.z + b0.w + b1.z + b1.w);
            size_t o = ((size_t)b * Hp + (by * (TH / 2) + 2 * g + pr)) * Wp
                       + (bx * (TW / 2) + 2 * x);
            *(float2*)(pool1 + o) = make_float2(pA0, pA1);
            *(float2*)(pool2 + o) = make_float2(pB0, pB1);
        }
    }

    // ---- Main: 14 staged rows per thread; on-the-fly horizontal conv;
    // vertical accumulation into registers.
    float acc[5][4][4];
#pragma unroll
    for (int p = 0; p < 5; ++p)
#pragma unroll
        for (int rr = 0; rr < 4; ++rr)
#pragma unroll
            for (int c = 0; c < 4; ++c) acc[p][rr][c] = 0.f;

    const int rowBase = 4 * g;
#pragma unroll 1
    for (int i = 0; i < 14; ++i) {
        const float* row1 = &s1[(rowBase + i) * SSTRIDE + 4 * x];
        const float* row2 = &s2[(rowBase + i) * SSTRIDE + 4 * x];
        float r1[17], r2[17];
        {
            float4 t;
            t = *(const float4*)(row1 + 0);  r1[0] = t.x; r1[1] = t.y; r1[2] = t.z; r1[3] = t.w;
            t = *(const float4*)(row1 + 4);  r1[4] = t.x; r1[5] = t.y; r1[6] = t.z; r1[7] = t.w;
            t = *(const float4*)(row1 + 8);  r1[8] = t.x; r1[9] = t.y; r1[10] = t.z; r1[11] = t.w;
            t = *(const float4*)(row1 + 12); r1[12] = t.x; r1[13] = t.y; r1[14] = t.z; r1[15] = t.w;
            r1[16] = row1[16];
            t = *(const float4*)(row2 + 0);  r2[0] = t.x; r2[1] = t.y; r2[2] = t.z; r2[3] = t.w;
            t = *(const float4*)(row2 + 4);  r2[4] = t.x; r2[5] = t.y; r2[6] = t.z; r2[7] = t.w;
            t = *(const float4*)(row2 + 8);  r2[8] = t.x; r2[9] = t.y; r2[10] = t.z; r2[11] = t.w;
            t = *(const float4*)(row2 + 12); r2[12] = t.x; r2[13] = t.y; r2[14] = t.z; r2[15] = t.w;
            r2[16] = row2[16];
        }
        // horizontal 11-tap conv at this row for 4 columns, 5 planes
        float hA[4], hB[4], hAA[4], hBB[4], hAB[4];
#pragma unroll
        for (int c = 0; c < 4; ++c) {
            float a = 0.f, bv = 0.f, aa = 0.f, bb = 0.f, ab = 0.f;
#pragma unroll
            for (int j = 0; j < WS; ++j) {
                float v1 = r1[3 + c + j], v2 = r2[3 + c + j];
                float wj = w[j];
                a  = fmaf(wj, v1, a);
                bv = fmaf(wj, v2, bv);
                aa = fmaf(wj, v1 * v1, aa);   // v1*v1 CSEs across c
                bb = fmaf(wj, v2 * v2, bb);
                ab = fmaf(wj, v1 * v2, ab);
            }
            hA[c] = a; hB[c] = bv; hAA[c] = aa; hBB[c] = bb; hAB[c] = ab;
        }
        // vertical accumulation: this h row feeds output rows rr with i-rr in [0,10]
#pragma unroll
        for (int rr = 0; rr < 4; ++rr) {
            int jv = i - rr;
            if (jv >= 0 && jv <= 10) {
                float wv = wg[jv];   // uniform LDS broadcast
#pragma unroll
                for (int c = 0; c < 4; ++c) {
                    acc[0][rr][c] = fmaf(wv, hA[c],  acc[0][rr][c]);
                    acc[1][rr][c] = fmaf(wv, hB[c],  acc[1][rr][c]);
                    acc[2][rr][c] = fmaf(wv, hAA[c], acc[2][rr][c]);
                    acc[3][rr][c] = fmaf(wv, hBB[c], acc[3][rr][c]);
                    acc[4][rr][c] = fmaf(wv, hAB[c], acc[4][rr][c]);
                }
            }
        }
    }

    // ---- SSIM/MCS per pixel + masked accumulation (mask only matters at level 4).
    const float C1 = 6.5025f;    // (0.01*255)^2
    const float C2 = 58.5225f;   // (0.03*255)^2
    const int Hv = min(TH, H - y0);
    const int Wv = min(TW, W - x0);
    float ssim_acc = 0.f, mcs_acc = 0.f;
#pragma unroll
    for (int rr = 0; rr < 4; ++rr) {
#pragma unroll
        for (int c = 0; c < 4; ++c) {
            float mu1 = acc[0][rr][c], mu2 = acc[1][rr][c];
            float mu1s = mu1 * mu1, mu2s = mu2 * mu2, mu12 = mu1 * mu2;
            float sig1 = acc[2][rr][c] - mu1s;
            float sig2 = acc[3][rr][c] - mu2s;
            float sig12 = acc[4][rr][c] - mu12;
            float V1 = 2.f * sig12 + C2;
            float V2 = sig1 + sig2 + C2;
            float D1 = mu1s + mu2s + C1;
            float inv = 1.0f / (V2 * D1);          // one division per pixel
            float ssim = (2.f * mu12 + C1) * V1 * inv;
            float mcs = V1 * D1 * inv;
            if ((4 * g + rr) < Hv && (4 * x + c) < Wv) {
                ssim_acc += ssim;
                mcs_acc += mcs;
            }
        }
    }

    // ---- Block reduction.
#pragma unroll
    for (int o = 32; o > 0; o >>= 1) {
        ssim_acc += __shfl_down(ssim_acc, o);
        mcs_acc += __shfl_down(mcs_acc, o);
    }
    int wave = tid >> 6, lane = tid & 63;
    if (lane == 0) {
        red[0][wave] = ssim_acc;
        red[1][wave] = mcs_acc;
    }
    __syncthreads();
    if (tid == 0) {
        float s = red[0][0] + red[0][1] + red[0][2] + red[0][3];
        float m = red[1][0] + red[1][1] + red[1][2] + red[1][3];
        size_t linear = ((size_t)blockIdx.z * gridDim.y + blockIdx.y) * gridDim.x + blockIdx.x;
        partials[2 * linear] = s;
        partials[2 * linear + 1] = m;
    }
}

__global__ __launch_bounds__(256) void finalize_kernel(
    const float* __restrict__ partials, float* __restrict__ out)
{
    __shared__ float lvl_s[5], lvl_m[5];
    __shared__ float red[2][4];
    const int nb[5] = {1024, 256, 64, 16, 16};
    const int off[5] = {0, 1024, 1280, 1344, 1360};
    const float npix[5] = {16.f * 512 * 512, 16.f * 256 * 256, 16.f * 128 * 128,
                           16.f * 64 * 64, 16.f * 32 * 32};
    const int tid = threadIdx.x;

    for (int l = 0; l < 5; ++l) {
        float s = 0.f, m = 0.f;
        for (int i = tid; i < nb[l]; i += 256) {
            s += partials[2 * (off[l] + i)];
            m += partials[2 * (off[l] + i) + 1];
        }
#pragma unroll
        for (int o = 32; o > 0; o >>= 1) {
            s += __shfl_down(s, o);
            m += __shfl_down(m, o);
        }
        int wave = tid >> 6, lane = tid & 63;
        if (lane == 0) {
            red[0][wave] = s;
            red[1][wave] = m;
        }
        __syncthreads();
        if (tid == 0) {
            lvl_s[l] = (red[0][0] + red[0][1] + red[0][2] + red[0][3]) / npix[l];
            lvl_m[l] = (red[1][0] + red[1][1] + red[1][2] + red[1][3]) / npix[l];
        }
        __syncthreads();
    }

    if (tid == 0) {
        const float w[5] = {0.0448f, 0.2856f, 0.3001f, 0.2363f, 0.1333f};
        float v = powf(lvl_m[0], w[0]) * powf(lvl_m[1], w[1]) * powf(lvl_m[2], w[2]) *
                  powf(lvl_m[3], w[3]) * powf(lvl_s[4], w[4]);
        v *= 0.5f;
        v = fminf(fmaxf(v, 0.f), 1.f);
        out[0] = v;
    }
}

extern "C" void kernel_launch(void* const* d_in, const int* in_sizes, int n_in,
                              void* d_out, int out_size, void* d_ws, size_t ws_size,
                              hipStream_t stream) {
    const float* img1 = (const float*)d_in[0];
    const float* img2 = (const float*)d_in[1];
    float* out = (float*)d_out;

    const int B = 16;

    // Workspace layout (floats): partials (1376 blocks * 2), then pooled pairs.
    float* wsf = (float*)d_ws;
    float* partials = wsf;
    float* p = wsf + 2752;
    float* p1_l1 = p; p += (size_t)B * 256 * 256;
    float* p2_l1 = p; p += (size_t)B * 256 * 256;
    float* p1_l2 = p; p += (size_t)B * 128 * 128;
    float* p2_l2 = p; p += (size_t)B * 128 * 128;
    float* p1_l3 = p; p += (size_t)B * 64 * 64;
    float* p2_l3 = p; p += (size_t)B * 64 * 64;
    float* p1_l4 = p; p += (size_t)B * 32 * 32;
    float* p2_l4 = p; p += (size_t)B * 32 * 32;

    const int part_off[5] = {0, 1024, 1280, 1344, 1360};

    dim3 block(256);

    // Level 0: 512x512, 8x8 tiles
    ssim_level_kernel<<<dim3(8, 8, B), block, 0, stream>>>(
        img1, img2, 512, 512, p1_l1, p2_l1, partials + 2 * part_off[0]);
    // Level 1: 256x256, 4x4 tiles
    ssim_level_kernel<<<dim3(4, 4, B), block, 0, stream>>>(
        p1_l1, p2_l1, 256, 256, p1_l2, p2_l2, partials + 2 * part_off[1]);
    // Level 2: 128x128, 2x2 tiles
    ssim_level_kernel<<<dim3(2, 2, B), block, 0, stream>>>(
        p1_l2, p2_l2, 128, 128, p1_l3, p2_l3, partials + 2 * part_off[2]);
    // Level 3: 64x64, 1 tile
    ssim_level_kernel<<<dim3(1, 1, B), block, 0, stream>>>(
        p1_l3, p2_l3, 64, 64, p1_l4, p2_l4, partials + 2 * part_off[3]);
    // Level 4: 32x32, 1 (partial) tile, no pooling
    ssim_level_kernel<<<dim3(1, 1, B), block, 0, stream>>>(
        p1_l4, p2_l4, 32, 32, nullptr, nullptr, partials + 2 * part_off[4]);

    finalize_kernel<<<1, block, 0, stream>>>(partials, out);
}

// Round 3
// 147.575 us; speedup vs baseline: 2.5491x; 2.5491x over previous
//
#include <hip/hip_runtime.h>
#include <math.h>

// MS-SSIM on (16,1,512,512) fp32, 5 levels, 11x11 gaussian (sigma=1.5), 2x2 avg-pool.
// Round-2 structure: 64x32 output tile, 256 threads.
//   Phase H: each task (row r, 4-col group) loads its 20-float window of both
//     images DIRECTLY from global (float4, L2 absorbs halo re-reads), forms
//     s=x+y, d=x-y, convolves 4 planes (s, d, s^2, d^2) horizontally, writes
//     aligned float4 to 4 LDS h-planes (stride 68, bank-spread).
//   Phase V: each thread owns 4 cols x 2 rows; 12 x 4 ds_read_b128 sliding
//     window, 4-plane vertical conv in 32 registers, SSIM/MCS via the s/d
//     identities (one division per pixel), masked block reduction.
// Pooling for the next level reads global directly (tiles always full for
// pooled levels). Per-block partials -> tiny finalize kernel.

#define WS 11
#define TW 64
#define TH 32
#define SROWS 42      // TH + 10 h-rows per tile
#define HSTRIDE 68    // 64 cols + 4 pad (bank spread)

__global__ __launch_bounds__(256) void ssim_level_kernel(
    const float* __restrict__ img1, const float* __restrict__ img2,
    int H, int W,
    float* __restrict__ pool1, float* __restrict__ pool2,  // null on last level
    float* __restrict__ partials)                           // 2 floats per block
{
    __shared__ float hS[SROWS * HSTRIDE];
    __shared__ float hD[SROWS * HSTRIDE];
    __shared__ float hS2[SROWS * HSTRIDE];
    __shared__ float hD2[SROWS * HSTRIDE];
    __shared__ float wgs[WS];
    __shared__ float red[2][4];

    const int tid = threadIdx.x;

    if (tid == 0) {
        double g[WS]; double sum = 0.0;
        for (int i = 0; i < WS; ++i) {
            double d = (double)(i - 5);
            g[i] = exp(-(d * d) / 4.5);   // 2*sigma^2 = 4.5
            sum += g[i];
        }
        for (int i = 0; i < WS; ++i) wgs[i] = (float)(g[i] / sum);
    }
    __syncthreads();

    float w[WS];
#pragma unroll
    for (int j = 0; j < WS; ++j) w[j] = wgs[j];

    const int bx = blockIdx.x, by = blockIdx.y, b = blockIdx.z;
    const int x0 = bx * TW, y0 = by * TH;
    const float* p1 = img1 + (size_t)b * H * W;
    const float* p2 = img2 + (size_t)b * H * W;

    // ---- Phase H: horizontal conv straight from global into LDS h-planes.
#pragma unroll 1
    for (int t = tid; t < SROWS * 16; t += 256) {
        int r = t >> 4, xg = t & 15;
        int gy = y0 - 5 + r;
        int gxb = x0 - 8 + 4 * xg;   // global col of f[0]
        float fs[20], fd[20];
        if (gy >= 0 && gy < H) {
            const float* r1p = p1 + (size_t)gy * W;
            const float* r2p = p2 + (size_t)gy * W;
#pragma unroll
            for (int k = 0; k < 5; ++k) {
                int gx = gxb + 4 * k;
                float4 a = make_float4(0.f, 0.f, 0.f, 0.f);
                float4 c = make_float4(0.f, 0.f, 0.f, 0.f);
                if (gx >= 0 && gx + 3 < W) {
                    a = *(const float4*)(r1p + gx);
                    c = *(const float4*)(r2p + gx);
                } else if (gx + 3 >= 0 && gx < W) {
                    float t1[4] = {0.f, 0.f, 0.f, 0.f};
                    float t2[4] = {0.f, 0.f, 0.f, 0.f};
#pragma unroll
                    for (int u = 0; u < 4; ++u) {
                        int gxx = gx + u;
                        if (gxx >= 0 && gxx < W) { t1[u] = r1p[gxx]; t2[u] = r2p[gxx]; }
                    }
                    a = make_float4(t1[0], t1[1], t1[2], t1[3]);
                    c = make_float4(t2[0], t2[1], t2[2], t2[3]);
                }
                fs[4 * k]     = a.x + c.x;  fd[4 * k]     = a.x - c.x;
                fs[4 * k + 1] = a.y + c.y;  fd[4 * k + 1] = a.y - c.y;
                fs[4 * k + 2] = a.z + c.z;  fd[4 * k + 2] = a.z - c.z;
                fs[4 * k + 3] = a.w + c.w;  fd[4 * k + 3] = a.w - c.w;
            }
        } else {
#pragma unroll
            for (int k = 0; k < 20; ++k) { fs[k] = 0.f; fd[k] = 0.f; }
        }
        // squares for window indices 3..16
        float qs[14], qd[14];
#pragma unroll
        for (int k = 0; k < 14; ++k) {
            qs[k] = fs[k + 3] * fs[k + 3];
            qd[k] = fd[k + 3] * fd[k + 3];
        }
        float oS[4], oD[4], oS2[4], oD2[4];
#pragma unroll
        for (int c = 0; c < 4; ++c) {
            float aS = 0.f, aD = 0.f, aS2 = 0.f, aD2 = 0.f;
#pragma unroll
            for (int j = 0; j < WS; ++j) {
                float wj = w[j];
                aS  = fmaf(wj, fs[3 + c + j], aS);
                aD  = fmaf(wj, fd[3 + c + j], aD);
                aS2 = fmaf(wj, qs[c + j], aS2);
                aD2 = fmaf(wj, qd[c + j], aD2);
            }
            oS[c] = aS; oD[c] = aD; oS2[c] = aS2; oD2[c] = aD2;
        }
        int ho = r * HSTRIDE + 4 * xg;
        *(float4*)&hS[ho]  = make_float4(oS[0], oS[1], oS[2], oS[3]);
        *(float4*)&hD[ho]  = make_float4(oD[0], oD[1], oD[2], oD[3]);
        *(float4*)&hS2[ho] = make_float4(oS2[0], oS2[1], oS2[2], oS2[3]);
        *(float4*)&hD2[ho] = make_float4(oD2[0], oD2[1], oD2[2], oD2[3]);
    }

    // ---- Fused 2x2 avg-pool (global reads; pooled levels always have full tiles).
    if (pool1 != nullptr) {
        int pc = tid & 15, pr = tid >> 4;       // pooled cols 2pc..2pc+1, row pr
        int Hp = H >> 1, Wp = W >> 1;
        int gy = y0 + 2 * pr, gx = x0 + 4 * pc;
        const float* r1a = p1 + (size_t)gy * W + gx;
        const float* r1b = r1a + W;
        const float* r2a = p2 + (size_t)gy * W + gx;
        const float* r2b = r2a + W;
        float4 a0 = *(const float4*)r1a, a1 = *(const float4*)r1b;
        float4 c0 = *(const float4*)r2a, c1 = *(const float4*)r2b;
        float2 px = make_float2(0.25f * (a0.x + a0.y + a1.x + a1.y),
                                0.25f * (a0.z + a0.w + a1.z + a1.w));
        float2 py = make_float2(0.25f * (c0.x + c0.y + c1.x + c1.y),
                                0.25f * (c0.z + c0.w + c1.z + c1.w));
        size_t o = ((size_t)b * Hp + (by * (TH / 2) + pr)) * Wp + (bx * (TW / 2) + 2 * pc);
        *(float2*)(pool1 + o) = px;
        *(float2*)(pool2 + o) = py;
    }

    __syncthreads();

    // ---- Phase V: vertical conv + SSIM. Thread owns cols 4x..4x+3, rows 2g..2g+1.
    const int x = tid & 15;
    const int g = tid >> 4;
    float accS[2][4], accD[2][4], accS2[2][4], accD2[2][4];
#pragma unroll
    for (int rr = 0; rr < 2; ++rr)
#pragma unroll
        for (int c = 0; c < 4; ++c) {
            accS[rr][c] = 0.f; accD[rr][c] = 0.f;
            accS2[rr][c] = 0.f; accD2[rr][c] = 0.f;
        }

#pragma unroll
    for (int r = 0; r < 12; ++r) {
        int ho = (2 * g + r) * HSTRIDE + 4 * x;
        float4 vS  = *(const float4*)&hS[ho];
        float4 vD  = *(const float4*)&hD[ho];
        float4 vS2 = *(const float4*)&hS2[ho];
        float4 vD2 = *(const float4*)&hD2[ho];
        float lS[4] = {vS.x, vS.y, vS.z, vS.w};
        float lD[4] = {vD.x, vD.y, vD.z, vD.w};
        float lS2[4] = {vS2.x, vS2.y, vS2.z, vS2.w};
        float lD2[4] = {vD2.x, vD2.y, vD2.z, vD2.w};
        if (r < 11) {
            float wv = w[r];
#pragma unroll
            for (int c = 0; c < 4; ++c) {
                accS[0][c]  = fmaf(wv, lS[c],  accS[0][c]);
                accD[0][c]  = fmaf(wv, lD[c],  accD[0][c]);
                accS2[0][c] = fmaf(wv, lS2[c], accS2[0][c]);
                accD2[0][c] = fmaf(wv, lD2[c], accD2[0][c]);
            }
        }
        if (r >= 1) {
            float wv = w[r - 1];
#pragma unroll
            for (int c = 0; c < 4; ++c) {
                accS[1][c]  = fmaf(wv, lS[c],  accS[1][c]);
                accD[1][c]  = fmaf(wv, lD[c],  accD[1][c]);
                accS2[1][c] = fmaf(wv, lS2[c], accS2[1][c]);
                accD2[1][c] = fmaf(wv, lD2[c], accD2[1][c]);
            }
        }
    }

    // ---- SSIM/MCS via s/d identities; masked accumulation.
    const float C1 = 6.5025f;    // (0.01*255)^2
    const float C2 = 58.5225f;   // (0.03*255)^2
    const int Hv = min(TH, H - y0);
    const int Wv = min(TW, W - x0);
    float sacc = 0.f, macc = 0.f;
#pragma unroll
    for (int rr = 0; rr < 2; ++rr) {
        int row = 2 * g + rr;
#pragma unroll
        for (int c = 0; c < 4; ++c) {
            float ms = accS[rr][c], md = accD[rr][c];
            float es = accS2[rr][c], ed = accD2[rr][c];
            float ms2 = ms * ms, md2 = md * md;
            float a  = 0.5f * (ms2 - md2);   // 2*mu1*mu2
            float bb = 0.5f * (ms2 + md2);   // mu1^2 + mu2^2
            float pq = 0.5f * (es - ed);     // 2*E[xy]
            float qq = 0.5f * (es + ed);     // E[x^2] + E[y^2]
            float V1 = (pq - a) + C2;        // 2*sig12 + C2
            float V2 = (qq - bb) + C2;       // sig1 + sig2 + C2
            float num = a + C1;
            float den = bb + C1;
            float inv = 1.0f / (den * V2);
            float sv = num * V1 * inv;
            float mv = V1 * den * inv;
            if (row < Hv && (4 * x + c) < Wv) { sacc += sv; macc += mv; }
        }
    }

    // ---- Block reduction.
#pragma unroll
    for (int o = 32; o > 0; o >>= 1) {
        sacc += __shfl_down(sacc, o);
        macc += __shfl_down(macc, o);
    }
    int wave = tid >> 6, lane = tid & 63;
    if (lane == 0) { red[0][wave] = sacc; red[1][wave] = macc; }
    __syncthreads();
    if (tid == 0) {
        float s = red[0][0] + red[0][1] + red[0][2] + red[0][3];
        float m = red[1][0] + red[1][1] + red[1][2] + red[1][3];
        size_t linear = ((size_t)blockIdx.z * gridDim.y + blockIdx.y) * gridDim.x + blockIdx.x;
        partials[2 * linear] = s;
        partials[2 * linear + 1] = m;
    }
}

__global__ __launch_bounds__(256) void finalize_kernel(
    const float* __restrict__ partials, float* __restrict__ out)
{
    __shared__ float lvl_s[5], lvl_m[5];
    __shared__ float red[2][4];
    const int nb[5] = {2048, 512, 128, 32, 16};
    const int off[5] = {0, 2048, 2560, 2688, 2720};
    const float npix[5] = {16.f * 512 * 512, 16.f * 256 * 256, 16.f * 128 * 128,
                           16.f * 64 * 64, 16.f * 32 * 32};
    const int tid = threadIdx.x;

    for (int l = 0; l < 5; ++l) {
        float s = 0.f, m = 0.f;
        for (int i = tid; i < nb[l]; i += 256) {
            s += partials[2 * (off[l] + i)];
            m += partials[2 * (off[l] + i) + 1];
        }
#pragma unroll
        for (int o = 32; o > 0; o >>= 1) {
            s += __shfl_down(s, o);
            m += __shfl_down(m, o);
        }
        int wave = tid >> 6, lane = tid & 63;
        if (lane == 0) { red[0][wave] = s; red[1][wave] = m; }
        __syncthreads();
        if (tid == 0) {
            lvl_s[l] = (red[0][0] + red[0][1] + red[0][2] + red[0][3]) / npix[l];
            lvl_m[l] = (red[1][0] + red[1][1] + red[1][2] + red[1][3]) / npix[l];
        }
        __syncthreads();
    }

    if (tid == 0) {
        const float w[5] = {0.0448f, 0.2856f, 0.3001f, 0.2363f, 0.1333f};
        float v = powf(lvl_m[0], w[0]) * powf(lvl_m[1], w[1]) * powf(lvl_m[2], w[2]) *
                  powf(lvl_m[3], w[3]) * powf(lvl_s[4], w[4]);
        v *= 0.5f;
        v = fminf(fmaxf(v, 0.f), 1.f);
        out[0] = v;
    }
}

extern "C" void kernel_launch(void* const* d_in, const int* in_sizes, int n_in,
                              void* d_out, int out_size, void* d_ws, size_t ws_size,
                              hipStream_t stream) {
    const float* img1 = (const float*)d_in[0];
    const float* img2 = (const float*)d_in[1];
    float* out = (float*)d_out;

    const int B = 16;

    // Workspace layout (floats): partials (2736 blocks * 2), then pooled pairs.
    float* wsf = (float*)d_ws;
    float* partials = wsf;
    float* p = wsf + 5472;
    float* p1_l1 = p; p += (size_t)B * 256 * 256;
    float* p2_l1 = p; p += (size_t)B * 256 * 256;
    float* p1_l2 = p; p += (size_t)B * 128 * 128;
    float* p2_l2 = p; p += (size_t)B * 128 * 128;
    float* p1_l3 = p; p += (size_t)B * 64 * 64;
    float* p2_l3 = p; p += (size_t)B * 64 * 64;
    float* p1_l4 = p; p += (size_t)B * 32 * 32;
    float* p2_l4 = p; p += (size_t)B * 32 * 32;

    const int part_off[5] = {0, 2048, 2560, 2688, 2720};

    dim3 block(256);

    // Level 0: 512x512, 8x16 tiles
    ssim_level_kernel<<<dim3(8, 16, B), block, 0, stream>>>(
        img1, img2, 512, 512, p1_l1, p2_l1, partials + 2 * part_off[0]);
    // Level 1: 256x256, 4x8 tiles
    ssim_level_kernel<<<dim3(4, 8, B), block, 0, stream>>>(
        p1_l1, p2_l1, 256, 256, p1_l2, p2_l2, partials + 2 * part_off[1]);
    // Level 2: 128x128, 2x4 tiles
    ssim_level_kernel<<<dim3(2, 4, B), block, 0, stream>>>(
        p1_l2, p2_l2, 128, 128, p1_l3, p2_l3, partials + 2 * part_off[2]);
    // Level 3: 64x64, 1x2 tiles
    ssim_level_kernel<<<dim3(1, 2, B), block, 0, stream>>>(
        p1_l3, p2_l3, 64, 64, p1_l4, p2_l4, partials + 2 * part_off[3]);
    // Level 4: 32x32, 1 tile (clipped), no pooling
    ssim_level_kernel<<<dim3(1, 1, B), block, 0, stream>>>(
        p1_l4, p2_l4, 32, 32, nullptr, nullptr, partials + 2 * part_off[4]);

    finalize_kernel<<<1, block, 0, stream>>>(partials, out);
}

// Round 4
// 129.438 us; speedup vs baseline: 2.9062x; 1.1401x over previous
//
#include <hip/hip_runtime.h>
#include <math.h>

// MS-SSIM on (16,1,512,512) fp32, 5 levels, 11x11 gaussian (sigma=1.5), 2x2 avg-pool.
// Round-3 structure (3 dispatches total):
//   1) pool_all_kernel: one block per 64x64 source region computes the whole
//      pool pyramid (L1..L4 chunks) hierarchically in LDS -> workspace.
//      Removes all inter-level dependencies.
//   2) ssim_fused_kernel: ALL levels in one 2736-block launch. Per-block
//      body = Round-2 proven tile: 64x32 output tile, Phase H (global->
//      4 LDS h-planes of s=x+y, d=x-y, s^2h, d^2h), Phase V (register
//      vertical conv, SSIM via s/d identities), per-block partials.
//   3) finalize_kernel: reduce partials, weighted product, clip, scalar out.

#define WS 11
#define TW 64
#define TH 32
#define SROWS 42      // TH + 10 h-rows per tile
#define HSTRIDE 68    // 64 cols + 4 pad (aligned b128, bank spread)

__device__ __forceinline__ void gauss_weights(float* w) {
    float s = 0.f;
#pragma unroll
    for (int j = 0; j < WS; ++j) {
        float d = (float)(j - 5);
        float e = expf(-d * d / 4.5f);   // 2*sigma^2 = 4.5
        w[j] = e;
        s += e;
    }
    float inv = 1.f / s;
#pragma unroll
    for (int j = 0; j < WS; ++j) w[j] *= inv;
}

// ---------------------------------------------------------------------------
// Kernel 1: full pool pyramid. Grid (8,8,16), 256 threads.
__global__ __launch_bounds__(256) void pool_all_kernel(
    const float* __restrict__ img1, const float* __restrict__ img2,
    float* __restrict__ l1a, float* __restrict__ l1b,
    float* __restrict__ l2a, float* __restrict__ l2b,
    float* __restrict__ l3a, float* __restrict__ l3b,
    float* __restrict__ l4a, float* __restrict__ l4b)
{
    __shared__ float buf[64 * 68];
    __shared__ float pl1[32 * 36];
    __shared__ float pl2[16 * 20];
    __shared__ float pl3[8 * 12];
    const int tid = threadIdx.x;
    const int rx = blockIdx.x, ry = blockIdx.y, b = blockIdx.z;
    const int gx0 = rx * 64, gy0 = ry * 64;

#pragma unroll 1
    for (int q = 0; q < 2; ++q) {
        const float* src = (q == 0 ? img1 : img2) + (size_t)b * 512 * 512;
        float* d1 = (q == 0 ? l1a : l1b) + (size_t)b * 256 * 256;
        float* d2 = (q == 0 ? l2a : l2b) + (size_t)b * 128 * 128;
        float* d3 = (q == 0 ? l3a : l3b) + (size_t)b * 64 * 64;
        float* d4 = (q == 0 ? l4a : l4b) + (size_t)b * 32 * 32;
        if (q) __syncthreads();
        // stage 64x64 tile
        for (int t = tid; t < 1024; t += 256) {
            int r = t >> 4, c4 = t & 15;
            float4 v = *(const float4*)(src + (size_t)(gy0 + r) * 512 + gx0 + 4 * c4);
            *(float4*)&buf[r * 68 + 4 * c4] = v;
        }
        __syncthreads();
        // L1: 32x32
        for (int t = tid; t < 1024; t += 256) {
            int r = t >> 5, c = t & 31;
            const float* p = &buf[(2 * r) * 68 + 2 * c];
            float v = 0.25f * ((p[0] + p[1]) + (p[68] + p[69]));
            pl1[r * 36 + c] = v;
            d1[(size_t)(32 * ry + r) * 256 + 32 * rx + c] = v;
        }
        __syncthreads();
        // L2: 16x16
        {
            int r = tid >> 4, c = tid & 15;
            const float* p = &pl1[(2 * r) * 36 + 2 * c];
            float v = 0.25f * ((p[0] + p[1]) + (p[36] + p[37]));
            pl2[r * 20 + c] = v;
            d2[(size_t)(16 * ry + r) * 128 + 16 * rx + c] = v;
        }
        __syncthreads();
        // L3: 8x8
        if (tid < 64) {
            int r = tid >> 3, c = tid & 7;
            const float* p = &pl2[(2 * r) * 20 + 2 * c];
            float v = 0.25f * ((p[0] + p[1]) + (p[20] + p[21]));
            pl3[r * 12 + c] = v;
            d3[(size_t)(8 * ry + r) * 64 + 8 * rx + c] = v;
        }
        __syncthreads();
        // L4: 4x4
        if (tid < 16) {
            int r = tid >> 2, c = tid & 3;
            const float* p = &pl3[(2 * r) * 12 + 2 * c];
            float v = 0.25f * ((p[0] + p[1]) + (p[12] + p[13]));
            d4[(size_t)(4 * ry + r) * 32 + 4 * rx + c] = v;
        }
    }
}

// ---------------------------------------------------------------------------
// Kernel 2: all SSIM levels fused. 1D grid of 2736 blocks, 256 threads.
// Block ranges: L0 [0,2048)  L1 [2048,2560)  L2 [2560,2688)
//               L3 [2688,2720)  L4 [2720,2736)
__global__ __launch_bounds__(256) void ssim_fused_kernel(
    const float* __restrict__ img1, const float* __restrict__ img2,
    const float* __restrict__ l1a, const float* __restrict__ l1b,
    const float* __restrict__ l2a, const float* __restrict__ l2b,
    const float* __restrict__ l3a, const float* __restrict__ l3b,
    const float* __restrict__ l4a, const float* __restrict__ l4b,
    float* __restrict__ partials)
{
    __shared__ float hS[SROWS * HSTRIDE];
    __shared__ float hD[SROWS * HSTRIDE];
    __shared__ float hS2[SROWS * HSTRIDE];
    __shared__ float hD2[SROWS * HSTRIDE];
    __shared__ float red[2][4];

    const int tid = threadIdx.x;
    const int lin = blockIdx.x;

    // ---- level decode (block-uniform)
    int level, base;
    if (lin < 2048)      { level = 0; base = 0; }
    else if (lin < 2560) { level = 1; base = 2048; }
    else if (lin < 2688) { level = 2; base = 2560; }
    else if (lin < 2720) { level = 3; base = 2688; }
    else                 { level = 4; base = 2720; }
    const int Wt[5]   = {512, 256, 128, 64, 32};
    const int ntxl[5] = {3, 2, 1, 0, 0};
    const int ntyl[5] = {4, 3, 2, 1, 0};
    const int W = Wt[level], H = W;
    const int li = lin - base;
    const int tx = li & ((1 << ntxl[level]) - 1);
    const int rem = li >> ntxl[level];
    const int ty = rem & ((1 << ntyl[level]) - 1);
    const int b = rem >> ntyl[level];

    const float* ip1; const float* ip2;
    if (level == 0)      { ip1 = img1; ip2 = img2; }
    else if (level == 1) { ip1 = l1a; ip2 = l1b; }
    else if (level == 2) { ip1 = l2a; ip2 = l2b; }
    else if (level == 3) { ip1 = l3a; ip2 = l3b; }
    else                 { ip1 = l4a; ip2 = l4b; }
    const float* p1 = ip1 + (size_t)b * H * W;
    const float* p2 = ip2 + (size_t)b * H * W;

    const int x0 = tx * TW, y0 = ty * TH;

    float w[WS];
    gauss_weights(w);

    // ---- Phase H: horizontal conv straight from global into LDS h-planes.
#pragma unroll 1
    for (int t = tid; t < SROWS * 16; t += 256) {
        int r = t >> 4, xg = t & 15;
        int gy = y0 - 5 + r;
        int gxb = x0 - 8 + 4 * xg;
        float fs[20], fd[20];
        if (gy >= 0 && gy < H) {
            const float* r1p = p1 + (size_t)gy * W;
            const float* r2p = p2 + (size_t)gy * W;
#pragma unroll
            for (int k = 0; k < 5; ++k) {
                int gx = gxb + 4 * k;
                float4 a = make_float4(0.f, 0.f, 0.f, 0.f);
                float4 c = make_float4(0.f, 0.f, 0.f, 0.f);
                if (gx >= 0 && gx + 3 < W) {
                    a = *(const float4*)(r1p + gx);
                    c = *(const float4*)(r2p + gx);
                } else if (gx + 3 >= 0 && gx < W) {
                    float t1[4] = {0.f, 0.f, 0.f, 0.f};
                    float t2[4] = {0.f, 0.f, 0.f, 0.f};
#pragma unroll
                    for (int u = 0; u < 4; ++u) {
                        int gxx = gx + u;
                        if (gxx >= 0 && gxx < W) { t1[u] = r1p[gxx]; t2[u] = r2p[gxx]; }
                    }
                    a = make_float4(t1[0], t1[1], t1[2], t1[3]);
                    c = make_float4(t2[0], t2[1], t2[2], t2[3]);
                }
                fs[4 * k]     = a.x + c.x;  fd[4 * k]     = a.x - c.x;
                fs[4 * k + 1] = a.y + c.y;  fd[4 * k + 1] = a.y - c.y;
                fs[4 * k + 2] = a.z + c.z;  fd[4 * k + 2] = a.z - c.z;
                fs[4 * k + 3] = a.w + c.w;  fd[4 * k + 3] = a.w - c.w;
            }
        } else {
#pragma unroll
            for (int k = 0; k < 20; ++k) { fs[k] = 0.f; fd[k] = 0.f; }
        }
        float qs[14], qd[14];
#pragma unroll
        for (int k = 0; k < 14; ++k) {
            qs[k] = fs[k + 3] * fs[k + 3];
            qd[k] = fd[k + 3] * fd[k + 3];
        }
        float oS[4], oD[4], oS2[4], oD2[4];
#pragma unroll
        for (int c = 0; c < 4; ++c) {
            float aS = 0.f, aD = 0.f, aS2 = 0.f, aD2 = 0.f;
#pragma unroll
            for (int j = 0; j < WS; ++j) {
                float wj = w[j];
                aS  = fmaf(wj, fs[3 + c + j], aS);
                aD  = fmaf(wj, fd[3 + c + j], aD);
                aS2 = fmaf(wj, qs[c + j], aS2);
                aD2 = fmaf(wj, qd[c + j], aD2);
            }
            oS[c] = aS; oD[c] = aD; oS2[c] = aS2; oD2[c] = aD2;
        }
        int ho = r * HSTRIDE + 4 * xg;
        *(float4*)&hS[ho]  = make_float4(oS[0], oS[1], oS[2], oS[3]);
        *(float4*)&hD[ho]  = make_float4(oD[0], oD[1], oD[2], oD[3]);
        *(float4*)&hS2[ho] = make_float4(oS2[0], oS2[1], oS2[2], oS2[3]);
        *(float4*)&hD2[ho] = make_float4(oD2[0], oD2[1], oD2[2], oD2[3]);
    }
    __syncthreads();

    // ---- Phase V: vertical conv + SSIM. Thread owns cols 4x..4x+3, rows 2g..2g+1.
    const int x = tid & 15;
    const int g = tid >> 4;
    float accS[2][4], accD[2][4], accS2[2][4], accD2[2][4];
#pragma unroll
    for (int rr = 0; rr < 2; ++rr)
#pragma unroll
        for (int c = 0; c < 4; ++c) {
            accS[rr][c] = 0.f; accD[rr][c] = 0.f;
            accS2[rr][c] = 0.f; accD2[rr][c] = 0.f;
        }

#pragma unroll
    for (int r = 0; r < 12; ++r) {
        int ho = (2 * g + r) * HSTRIDE + 4 * x;
        float4 vS  = *(const float4*)&hS[ho];
        float4 vD  = *(const float4*)&hD[ho];
        float4 vS2 = *(const float4*)&hS2[ho];
        float4 vD2 = *(const float4*)&hD2[ho];
        float lS[4] = {vS.x, vS.y, vS.z, vS.w};
        float lD[4] = {vD.x, vD.y, vD.z, vD.w};
        float lS2[4] = {vS2.x, vS2.y, vS2.z, vS2.w};
        float lD2[4] = {vD2.x, vD2.y, vD2.z, vD2.w};
        if (r < 11) {
            float wv = w[r];
#pragma unroll
            for (int c = 0; c < 4; ++c) {
                accS[0][c]  = fmaf(wv, lS[c],  accS[0][c]);
                accD[0][c]  = fmaf(wv, lD[c],  accD[0][c]);
                accS2[0][c] = fmaf(wv, lS2[c], accS2[0][c]);
                accD2[0][c] = fmaf(wv, lD2[c], accD2[0][c]);
            }
        }
        if (r >= 1) {
            float wv = w[r - 1];
#pragma unroll
            for (int c = 0; c < 4; ++c) {
                accS[1][c]  = fmaf(wv, lS[c],  accS[1][c]);
                accD[1][c]  = fmaf(wv, lD[c],  accD[1][c]);
                accS2[1][c] = fmaf(wv, lS2[c], accS2[1][c]);
                accD2[1][c] = fmaf(wv, lD2[c], accD2[1][c]);
            }
        }
    }

    // ---- SSIM/MCS via s/d identities; masked accumulation.
    const float C1 = 6.5025f;
    const float C2 = 58.5225f;
    const int Hv = min(TH, H - y0);
    const int Wv = min(TW, W - x0);
    float sacc = 0.f, macc = 0.f;
#pragma unroll
    for (int rr = 0; rr < 2; ++rr) {
        int row = 2 * g + rr;
#pragma unroll
        for (int c = 0; c < 4; ++c) {
            float ms = accS[rr][c], md = accD[rr][c];
            float es = accS2[rr][c], ed = accD2[rr][c];
            float ms2 = ms * ms, md2 = md * md;
            float a  = 0.5f * (ms2 - md2);   // 2*mu1*mu2
            float bb = 0.5f * (ms2 + md2);   // mu1^2 + mu2^2
            float pq = 0.5f * (es - ed);     // 2*E[xy]
            float qq = 0.5f * (es + ed);     // E[x^2] + E[y^2]
            float V1 = (pq - a) + C2;
            float V2 = (qq - bb) + C2;
            float num = a + C1;
            float den = bb + C1;
            float inv = 1.0f / (den * V2);
            float sv = num * V1 * inv;
            float mv = V1 * den * inv;
            if (row < Hv && (4 * x + c) < Wv) { sacc += sv; macc += mv; }
        }
    }

    // ---- Block reduction.
#pragma unroll
    for (int o = 32; o > 0; o >>= 1) {
        sacc += __shfl_down(sacc, o);
        macc += __shfl_down(macc, o);
    }
    int wave = tid >> 6, lane = tid & 63;
    if (lane == 0) { red[0][wave] = sacc; red[1][wave] = macc; }
    __syncthreads();
    if (tid == 0) {
        float s = red[0][0] + red[0][1] + red[0][2] + red[0][3];
        float m = red[1][0] + red[1][1] + red[1][2] + red[1][3];
        partials[2 * lin] = s;
        partials[2 * lin + 1] = m;
    }
}

// ---------------------------------------------------------------------------
__global__ __launch_bounds__(256) void finalize_kernel(
    const float* __restrict__ partials, float* __restrict__ out)
{
    __shared__ float lvl_s[5], lvl_m[5];
    __shared__ float red[2][4];
    const int nb[5] = {2048, 512, 128, 32, 16};
    const int off[5] = {0, 2048, 2560, 2688, 2720};
    const float npix[5] = {16.f * 512 * 512, 16.f * 256 * 256, 16.f * 128 * 128,
                           16.f * 64 * 64, 16.f * 32 * 32};
    const int tid = threadIdx.x;

    for (int l = 0; l < 5; ++l) {
        float s = 0.f, m = 0.f;
        for (int i = tid; i < nb[l]; i += 256) {
            s += partials[2 * (off[l] + i)];
            m += partials[2 * (off[l] + i) + 1];
        }
#pragma unroll
        for (int o = 32; o > 0; o >>= 1) {
            s += __shfl_down(s, o);
            m += __shfl_down(m, o);
        }
        int wave = tid >> 6, lane = tid & 63;
        if (lane == 0) { red[0][wave] = s; red[1][wave] = m; }
        __syncthreads();
        if (tid == 0) {
            lvl_s[l] = (red[0][0] + red[0][1] + red[0][2] + red[0][3]) / npix[l];
            lvl_m[l] = (red[1][0] + red[1][1] + red[1][2] + red[1][3]) / npix[l];
        }
        __syncthreads();
    }

    if (tid == 0) {
        const float w[5] = {0.0448f, 0.2856f, 0.3001f, 0.2363f, 0.1333f};
        float v = powf(lvl_m[0], w[0]) * powf(lvl_m[1], w[1]) * powf(lvl_m[2], w[2]) *
                  powf(lvl_m[3], w[3]) * powf(lvl_s[4], w[4]);
        v *= 0.5f;
        v = fminf(fmaxf(v, 0.f), 1.f);
        out[0] = v;
    }
}

extern "C" void kernel_launch(void* const* d_in, const int* in_sizes, int n_in,
                              void* d_out, int out_size, void* d_ws, size_t ws_size,
                              hipStream_t stream) {
    const float* img1 = (const float*)d_in[0];
    const float* img2 = (const float*)d_in[1];
    float* out = (float*)d_out;

    const int B = 16;

    // Workspace layout (floats): partials (2736 * 2), then pooled pairs.
    float* wsf = (float*)d_ws;
    float* partials = wsf;
    float* p = wsf + 5472;
    float* l1a = p; p += (size_t)B * 256 * 256;
    float* l1b = p; p += (size_t)B * 256 * 256;
    float* l2a = p; p += (size_t)B * 128 * 128;
    float* l2b = p; p += (size_t)B * 128 * 128;
    float* l3a = p; p += (size_t)B * 64 * 64;
    float* l3b = p; p += (size_t)B * 64 * 64;
    float* l4a = p; p += (size_t)B * 32 * 32;
    float* l4b = p; p += (size_t)B * 32 * 32;

    dim3 block(256);

    pool_all_kernel<<<dim3(8, 8, B), block, 0, stream>>>(
        img1, img2, l1a, l1b, l2a, l2b, l3a, l3b, l4a, l4b);

    ssim_fused_kernel<<<dim3(2736), block, 0, stream>>>(
        img1, img2, l1a, l1b, l2a, l2b, l3a, l3b, l4a, l4b, partials);

    finalize_kernel<<<1, block, 0, stream>>>(partials, out);
}

// Round 5
// 124.552 us; speedup vs baseline: 3.0202x; 1.0392x over previous
//
#include <hip/hip_runtime.h>
#include <math.h>

// MS-SSIM on (16,1,512,512) fp32, 5 levels, 11x11 gaussian (sigma=1.5), 2x2 avg-pool.
// Round-4 structure (3 dispatches):
//   A) ssim_l0_pool_kernel (2048 blocks): L0 SSIM (proven 64x32 tile, s/d
//      4-plane separable conv) + emits the FULL pool pyramid chunk for its
//      tile: L1 by all threads (LDS pl1 + global), L2..L4 by wave 0 reading
//      pl1 register-hierarchically (no extra barriers, no races).
//   B) ssim_rest_kernel (688 blocks): SSIM levels 1..4 from pooled arrays.
//   C) finalize_kernel: reduce partials, weighted product, clip, scalar out.

#define WS 11
#define TW 64
#define TH 32
#define SROWS 42      // TH + 10 h-rows per tile
#define HSTRIDE 68    // 64 cols + 4 pad (aligned b128, bank spread)

__device__ __forceinline__ void gauss_weights(float* w) {
    float s = 0.f;
#pragma unroll
    for (int j = 0; j < WS; ++j) {
        float d = (float)(j - 5);
        float e = expf(-d * d / 4.5f);   // 2*sigma^2 = 4.5
        w[j] = e;
        s += e;
    }
    float inv = 1.f / s;
#pragma unroll
    for (int j = 0; j < WS; ++j) w[j] *= inv;
}

// Shared SSIM tile body: phase H from (p1,p2) HxW image at tile (x0,y0) into
// LDS h-planes; phase V + masked partial sums. Returns via *sout,*mout on tid0.
__device__ __forceinline__ void ssim_tile(
    const float* __restrict__ p1, const float* __restrict__ p2,
    int H, int W, int x0, int y0, const float* w,
    float* hS, float* hD, float* hS2, float* hD2,
    float red[2][4], float* __restrict__ partials, int part_idx)
{
    const int tid = threadIdx.x;

    // ---- Phase H
#pragma unroll 1
    for (int t = tid; t < SROWS * 16; t += 256) {
        int r = t >> 4, xg = t & 15;
        int gy = y0 - 5 + r;
        int gxb = x0 - 8 + 4 * xg;
        float fs[20], fd[20];
        if (gy >= 0 && gy < H) {
            const float* r1p = p1 + (size_t)gy * W;
            const float* r2p = p2 + (size_t)gy * W;
#pragma unroll
            for (int k = 0; k < 5; ++k) {
                int gx = gxb + 4 * k;
                float4 a = make_float4(0.f, 0.f, 0.f, 0.f);
                float4 c = make_float4(0.f, 0.f, 0.f, 0.f);
                if (gx >= 0 && gx + 3 < W) {
                    a = *(const float4*)(r1p + gx);
                    c = *(const float4*)(r2p + gx);
                } else if (gx + 3 >= 0 && gx < W) {
                    float t1[4] = {0.f, 0.f, 0.f, 0.f};
                    float t2[4] = {0.f, 0.f, 0.f, 0.f};
#pragma unroll
                    for (int u = 0; u < 4; ++u) {
                        int gxx = gx + u;
                        if (gxx >= 0 && gxx < W) { t1[u] = r1p[gxx]; t2[u] = r2p[gxx]; }
                    }
                    a = make_float4(t1[0], t1[1], t1[2], t1[3]);
                    c = make_float4(t2[0], t2[1], t2[2], t2[3]);
                }
                fs[4 * k]     = a.x + c.x;  fd[4 * k]     = a.x - c.x;
                fs[4 * k + 1] = a.y + c.y;  fd[4 * k + 1] = a.y - c.y;
                fs[4 * k + 2] = a.z + c.z;  fd[4 * k + 2] = a.z - c.z;
                fs[4 * k + 3] = a.w + c.w;  fd[4 * k + 3] = a.w - c.w;
            }
        } else {
#pragma unroll
            for (int k = 0; k < 20; ++k) { fs[k] = 0.f; fd[k] = 0.f; }
        }
        float qs[14], qd[14];
#pragma unroll
        for (int k = 0; k < 14; ++k) {
            qs[k] = fs[k + 3] * fs[k + 3];
            qd[k] = fd[k + 3] * fd[k + 3];
        }
        float oS[4], oD[4], oS2[4], oD2[4];
#pragma unroll
        for (int c = 0; c < 4; ++c) {
            float aS = 0.f, aD = 0.f, aS2 = 0.f, aD2 = 0.f;
#pragma unroll
            for (int j = 0; j < WS; ++j) {
                float wj = w[j];
                aS  = fmaf(wj, fs[3 + c + j], aS);
                aD  = fmaf(wj, fd[3 + c + j], aD);
                aS2 = fmaf(wj, qs[c + j], aS2);
                aD2 = fmaf(wj, qd[c + j], aD2);
            }
            oS[c] = aS; oD[c] = aD; oS2[c] = aS2; oD2[c] = aD2;
        }
        int ho = r * HSTRIDE + 4 * xg;
        *(float4*)&hS[ho]  = make_float4(oS[0], oS[1], oS[2], oS[3]);
        *(float4*)&hD[ho]  = make_float4(oD[0], oD[1], oD[2], oD[3]);
        *(float4*)&hS2[ho] = make_float4(oS2[0], oS2[1], oS2[2], oS2[3]);
        *(float4*)&hD2[ho] = make_float4(oD2[0], oD2[1], oD2[2], oD2[3]);
    }
    __syncthreads();

    // ---- Phase V
    const int x = tid & 15;
    const int g = tid >> 4;
    float accS[2][4], accD[2][4], accS2[2][4], accD2[2][4];
#pragma unroll
    for (int rr = 0; rr < 2; ++rr)
#pragma unroll
        for (int c = 0; c < 4; ++c) {
            accS[rr][c] = 0.f; accD[rr][c] = 0.f;
            accS2[rr][c] = 0.f; accD2[rr][c] = 0.f;
        }

#pragma unroll
    for (int r = 0; r < 12; ++r) {
        int ho = (2 * g + r) * HSTRIDE + 4 * x;
        float4 vS  = *(const float4*)&hS[ho];
        float4 vD  = *(const float4*)&hD[ho];
        float4 vS2 = *(const float4*)&hS2[ho];
        float4 vD2 = *(const float4*)&hD2[ho];
        float lS[4] = {vS.x, vS.y, vS.z, vS.w};
        float lD[4] = {vD.x, vD.y, vD.z, vD.w};
        float lS2[4] = {vS2.x, vS2.y, vS2.z, vS2.w};
        float lD2[4] = {vD2.x, vD2.y, vD2.z, vD2.w};
        if (r < 11) {
            float wv = w[r];
#pragma unroll
            for (int c = 0; c < 4; ++c) {
                accS[0][c]  = fmaf(wv, lS[c],  accS[0][c]);
                accD[0][c]  = fmaf(wv, lD[c],  accD[0][c]);
                accS2[0][c] = fmaf(wv, lS2[c], accS2[0][c]);
                accD2[0][c] = fmaf(wv, lD2[c], accD2[0][c]);
            }
        }
        if (r >= 1) {
            float wv = w[r - 1];
#pragma unroll
            for (int c = 0; c < 4; ++c) {
                accS[1][c]  = fmaf(wv, lS[c],  accS[1][c]);
                accD[1][c]  = fmaf(wv, lD[c],  accD[1][c]);
                accS2[1][c] = fmaf(wv, lS2[c], accS2[1][c]);
                accD2[1][c] = fmaf(wv, lD2[c], accD2[1][c]);
            }
        }
    }

    const float C1 = 6.5025f;
    const float C2 = 58.5225f;
    const int Hv = min(TH, H - y0);
    const int Wv = min(TW, W - x0);
    float sacc = 0.f, macc = 0.f;
#pragma unroll
    for (int rr = 0; rr < 2; ++rr) {
        int row = 2 * g + rr;
#pragma unroll
        for (int c = 0; c < 4; ++c) {
            float ms = accS[rr][c], md = accD[rr][c];
            float es = accS2[rr][c], ed = accD2[rr][c];
            float ms2 = ms * ms, md2 = md * md;
            float a  = 0.5f * (ms2 - md2);
            float bb = 0.5f * (ms2 + md2);
            float pq = 0.5f * (es - ed);
            float qq = 0.5f * (es + ed);
            float V1 = (pq - a) + C2;
            float V2 = (qq - bb) + C2;
            float num = a + C1;
            float den = bb + C1;
            float inv = 1.0f / (den * V2);
            float sv = num * V1 * inv;
            float mv = V1 * den * inv;
            if (row < Hv && (4 * x + c) < Wv) { sacc += sv; macc += mv; }
        }
    }

#pragma unroll
    for (int o = 32; o > 0; o >>= 1) {
        sacc += __shfl_down(sacc, o);
        macc += __shfl_down(macc, o);
    }
    int wave = tid >> 6, lane = tid & 63;
    if (lane == 0) { red[0][wave] = sacc; red[1][wave] = macc; }
    __syncthreads();
    if (tid == 0) {
        float s = red[0][0] + red[0][1] + red[0][2] + red[0][3];
        float m = red[1][0] + red[1][1] + red[1][2] + red[1][3];
        partials[2 * part_idx] = s;
        partials[2 * part_idx + 1] = m;
    }
}

// ---------------------------------------------------------------------------
// Kernel A: L0 SSIM + full pool pyramid. Grid (8,16,16), 256 threads.
__global__ __launch_bounds__(256) void ssim_l0_pool_kernel(
    const float* __restrict__ img1, const float* __restrict__ img2,
    float* __restrict__ l1a, float* __restrict__ l1b,
    float* __restrict__ l2a, float* __restrict__ l2b,
    float* __restrict__ l3a, float* __restrict__ l3b,
    float* __restrict__ l4a, float* __restrict__ l4b,
    float* __restrict__ partials)
{
    __shared__ float hS[SROWS * HSTRIDE];
    __shared__ float hD[SROWS * HSTRIDE];
    __shared__ float hS2[SROWS * HSTRIDE];
    __shared__ float hD2[SROWS * HSTRIDE];
    __shared__ float pl1a[16 * 36];
    __shared__ float pl1b[16 * 36];
    __shared__ float red[2][4];

    const int tid = threadIdx.x;
    const int tx = blockIdx.x, ty = blockIdx.y, b = blockIdx.z;
    const int x0 = tx * TW, y0 = ty * TH;
    const float* p1 = img1 + (size_t)b * 512 * 512;
    const float* p2 = img2 + (size_t)b * 512 * 512;

    float w[WS];
    gauss_weights(w);

    // ===== Phase H (inline of ssim_tile's H to interleave pooling before sync)
#pragma unroll 1
    for (int t = tid; t < SROWS * 16; t += 256) {
        int r = t >> 4, xg = t & 15;
        int gy = y0 - 5 + r;
        int gxb = x0 - 8 + 4 * xg;
        float fs[20], fd[20];
        if (gy >= 0 && gy < 512) {
            const float* r1p = p1 + (size_t)gy * 512;
            const float* r2p = p2 + (size_t)gy * 512;
#pragma unroll
            for (int k = 0; k < 5; ++k) {
                int gx = gxb + 4 * k;
                float4 a = make_float4(0.f, 0.f, 0.f, 0.f);
                float4 c = make_float4(0.f, 0.f, 0.f, 0.f);
                if (gx >= 0 && gx + 3 < 512) {
                    a = *(const float4*)(r1p + gx);
                    c = *(const float4*)(r2p + gx);
                } else if (gx + 3 >= 0 && gx < 512) {
                    float t1[4] = {0.f, 0.f, 0.f, 0.f};
                    float t2[4] = {0.f, 0.f, 0.f, 0.f};
#pragma unroll
                    for (int u = 0; u < 4; ++u) {
                        int gxx = gx + u;
                        if (gxx >= 0 && gxx < 512) { t1[u] = r1p[gxx]; t2[u] = r2p[gxx]; }
                    }
                    a = make_float4(t1[0], t1[1], t1[2], t1[3]);
                    c = make_float4(t2[0], t2[1], t2[2], t2[3]);
                }
                fs[4 * k]     = a.x + c.x;  fd[4 * k]     = a.x - c.x;
                fs[4 * k + 1] = a.y + c.y;  fd[4 * k + 1] = a.y - c.y;
                fs[4 * k + 2] = a.z + c.z;  fd[4 * k + 2] = a.z - c.z;
                fs[4 * k + 3] = a.w + c.w;  fd[4 * k + 3] = a.w - c.w;
            }
        } else {
#pragma unroll
            for (int k = 0; k < 20; ++k) { fs[k] = 0.f; fd[k] = 0.f; }
        }
        float qs[14], qd[14];
#pragma unroll
        for (int k = 0; k < 14; ++k) {
            qs[k] = fs[k + 3] * fs[k + 3];
            qd[k] = fd[k + 3] * fd[k + 3];
        }
        float oS[4], oD[4], oS2[4], oD2[4];
#pragma unroll
        for (int c = 0; c < 4; ++c) {
            float aS = 0.f, aD = 0.f, aS2 = 0.f, aD2 = 0.f;
#pragma unroll
            for (int j = 0; j < WS; ++j) {
                float wj = w[j];
                aS  = fmaf(wj, fs[3 + c + j], aS);
                aD  = fmaf(wj, fd[3 + c + j], aD);
                aS2 = fmaf(wj, qs[c + j], aS2);
                aD2 = fmaf(wj, qd[c + j], aD2);
            }
            oS[c] = aS; oD[c] = aD; oS2[c] = aS2; oD2[c] = aD2;
        }
        int ho = r * HSTRIDE + 4 * xg;
        *(float4*)&hS[ho]  = make_float4(oS[0], oS[1], oS[2], oS[3]);
        *(float4*)&hD[ho]  = make_float4(oD[0], oD[1], oD[2], oD[3]);
        *(float4*)&hS2[ho] = make_float4(oS2[0], oS2[1], oS2[2], oS2[3]);
        *(float4*)&hD2[ho] = make_float4(oD2[0], oD2[1], oD2[2], oD2[3]);
    }

    // ===== Pool L1 for this tile (all threads; source is L1-cache hot).
    for (int t = tid; t < 512; t += 256) {
        int r = t >> 5, c = t & 31;
        int gy = y0 + 2 * r, gx = x0 + 2 * c;
        const float* a0 = p1 + (size_t)gy * 512 + gx;
        const float* c0 = p2 + (size_t)gy * 512 + gx;
        float2 u0 = *(const float2*)a0;
        float2 u1 = *(const float2*)(a0 + 512);
        float2 t0 = *(const float2*)c0;
        float2 t1 = *(const float2*)(c0 + 512);
        float v1 = 0.25f * ((u0.x + u0.y) + (u1.x + u1.y));
        float v2 = 0.25f * ((t0.x + t0.y) + (t1.x + t1.y));
        size_t o1 = (size_t)b * 256 * 256 + (size_t)(y0 / 2 + r) * 256 + (x0 / 2 + c);
        l1a[o1] = v1;
        l1b[o1] = v2;
        pl1a[r * 36 + c] = v1;
        pl1b[r * 36 + c] = v2;
    }
    __syncthreads();   // h-planes AND pl1 complete

    // ===== Wave 0: deeper pools, register-hierarchical from pl1 (race-free).
    if (tid < 64) {
        int lane = tid;
        // L2: 8 rows x 16 cols
#pragma unroll
        for (int t = lane; t < 128; t += 64) {
            int r = t >> 4, c = t & 15;
            int R = 2 * r, C = 2 * c;
            float v1 = 0.25f * ((pl1a[R * 36 + C] + pl1a[R * 36 + C + 1]) +
                                (pl1a[(R + 1) * 36 + C] + pl1a[(R + 1) * 36 + C + 1]));
            float v2 = 0.25f * ((pl1b[R * 36 + C] + pl1b[R * 36 + C + 1]) +
                                (pl1b[(R + 1) * 36 + C] + pl1b[(R + 1) * 36 + C + 1]));
            size_t o = (size_t)b * 128 * 128 + (size_t)(y0 / 4 + r) * 128 + (x0 / 4 + c);
            l2a[o] = v1;
            l2b[o] = v2;
        }
        // L3: 4 rows x 8 cols (lanes 0..31), each from a 4x4 pl1 block
        if (lane < 32) {
            int r = lane >> 3, c = lane & 7;
            float q1[2][2], q2[2][2];
#pragma unroll
            for (int i = 0; i < 2; ++i)
#pragma unroll
                for (int j = 0; j < 2; ++j) {
                    int R = 4 * r + 2 * i, C = 4 * c + 2 * j;
                    q1[i][j] = 0.25f * ((pl1a[R * 36 + C] + pl1a[R * 36 + C + 1]) +
                                        (pl1a[(R + 1) * 36 + C] + pl1a[(R + 1) * 36 + C + 1]));
                    q2[i][j] = 0.25f * ((pl1b[R * 36 + C] + pl1b[R * 36 + C + 1]) +
                                        (pl1b[(R + 1) * 36 + C] + pl1b[(R + 1) * 36 + C + 1]));
                }
            float v1 = 0.25f * ((q1[0][0] + q1[0][1]) + (q1[1][0] + q1[1][1]));
            float v2 = 0.25f * ((q2[0][0] + q2[0][1]) + (q2[1][0] + q2[1][1]));
            size_t o = (size_t)b * 64 * 64 + (size_t)(y0 / 8 + r) * 64 + (x0 / 8 + c);
            l3a[o] = v1;
            l3b[o] = v2;
        }
        // L4: 2 rows x 4 cols (lanes 0..7), each from an 8x8 pl1 block
        if (lane < 8) {
            int r = lane >> 2, c = lane & 3;
            float p3a[2][2], p3b[2][2];
#pragma unroll
            for (int i3 = 0; i3 < 2; ++i3)
#pragma unroll
                for (int j3 = 0; j3 < 2; ++j3) {
                    float p2a[2][2], p2b[2][2];
#pragma unroll
                    for (int i2 = 0; i2 < 2; ++i2)
#pragma unroll
                        for (int j2 = 0; j2 < 2; ++j2) {
                            int R = 8 * r + 4 * i3 + 2 * i2;
                            int C = 8 * c + 4 * j3 + 2 * j2;
                            p2a[i2][j2] = 0.25f * ((pl1a[R * 36 + C] + pl1a[R * 36 + C + 1]) +
                                                   (pl1a[(R + 1) * 36 + C] + pl1a[(R + 1) * 36 + C + 1]));
                            p2b[i2][j2] = 0.25f * ((pl1b[R * 36 + C] + pl1b[R * 36 + C + 1]) +
                                                   (pl1b[(R + 1) * 36 + C] + pl1b[(R + 1) * 36 + C + 1]));
                        }
                    p3a[i3][j3] = 0.25f * ((p2a[0][0] + p2a[0][1]) + (p2a[1][0] + p2a[1][1]));
                    p3b[i3][j3] = 0.25f * ((p2b[0][0] + p2b[0][1]) + (p2b[1][0] + p2b[1][1]));
                }
            float v1 = 0.25f * ((p3a[0][0] + p3a[0][1]) + (p3a[1][0] + p3a[1][1]));
            float v2 = 0.25f * ((p3b[0][0] + p3b[0][1]) + (p3b[1][0] + p3b[1][1]));
            size_t o = (size_t)b * 32 * 32 + (size_t)(y0 / 16 + r) * 32 + (x0 / 16 + c);
            l4a[o] = v1;
            l4b[o] = v2;
        }
    }

    // ===== Phase V + reduction (identical math to ssim_tile's V).
    {
        const int x = tid & 15;
        const int g = tid >> 4;
        float accS[2][4], accD[2][4], accS2[2][4], accD2[2][4];
#pragma unroll
        for (int rr = 0; rr < 2; ++rr)
#pragma unroll
            for (int c = 0; c < 4; ++c) {
                accS[rr][c] = 0.f; accD[rr][c] = 0.f;
                accS2[rr][c] = 0.f; accD2[rr][c] = 0.f;
            }

#pragma unroll
        for (int r = 0; r < 12; ++r) {
            int ho = (2 * g + r) * HSTRIDE + 4 * x;
            float4 vS  = *(const float4*)&hS[ho];
            float4 vD  = *(const float4*)&hD[ho];
            float4 vS2 = *(const float4*)&hS2[ho];
            float4 vD2 = *(const float4*)&hD2[ho];
            float lS[4] = {vS.x, vS.y, vS.z, vS.w};
            float lD[4] = {vD.x, vD.y, vD.z, vD.w};
            float lS2[4] = {vS2.x, vS2.y, vS2.z, vS2.w};
            float lD2[4] = {vD2.x, vD2.y, vD2.z, vD2.w};
            if (r < 11) {
                float wv = w[r];
#pragma unroll
                for (int c = 0; c < 4; ++c) {
                    accS[0][c]  = fmaf(wv, lS[c],  accS[0][c]);
                    accD[0][c]  = fmaf(wv, lD[c],  accD[0][c]);
                    accS2[0][c] = fmaf(wv, lS2[c], accS2[0][c]);
                    accD2[0][c] = fmaf(wv, lD2[c], accD2[0][c]);
                }
            }
            if (r >= 1) {
                float wv = w[r - 1];
#pragma unroll
                for (int c = 0; c < 4; ++c) {
                    accS[1][c]  = fmaf(wv, lS[c],  accS[1][c]);
                    accD[1][c]  = fmaf(wv, lD[c],  accD[1][c]);
                    accS2[1][c] = fmaf(wv, lS2[c], accS2[1][c]);
                    accD2[1][c] = fmaf(wv, lD2[c], accD2[1][c]);
                }
            }
        }

        const float C1 = 6.5025f;
        const float C2 = 58.5225f;
        float sacc = 0.f, macc = 0.f;
#pragma unroll
        for (int rr = 0; rr < 2; ++rr) {
#pragma unroll
            for (int c = 0; c < 4; ++c) {
                float ms = accS[rr][c], md = accD[rr][c];
                float es = accS2[rr][c], ed = accD2[rr][c];
                float ms2 = ms * ms, md2 = md * md;
                float a  = 0.5f * (ms2 - md2);
                float bb = 0.5f * (ms2 + md2);
                float pq = 0.5f * (es - ed);
                float qq = 0.5f * (es + ed);
                float V1 = (pq - a) + C2;
                float V2 = (qq - bb) + C2;
                float num = a + C1;
                float den = bb + C1;
                float inv = 1.0f / (den * V2);
                sacc += num * V1 * inv;
                macc += V1 * den * inv;
            }
        }

#pragma unroll
        for (int o = 32; o > 0; o >>= 1) {
            sacc += __shfl_down(sacc, o);
            macc += __shfl_down(macc, o);
        }
        int wave = tid >> 6, lane = tid & 63;
        if (lane == 0) { red[0][wave] = sacc; red[1][wave] = macc; }
        __syncthreads();
        if (tid == 0) {
            float s = red[0][0] + red[0][1] + red[0][2] + red[0][3];
            float m = red[1][0] + red[1][1] + red[1][2] + red[1][3];
            int linear = ((b * 16 + ty) * 8) + tx;
            partials[2 * linear] = s;
            partials[2 * linear + 1] = m;
        }
    }
}

// ---------------------------------------------------------------------------
// Kernel B: SSIM levels 1..4. 688 blocks.
// Ranges: L1 [0,512)  L2 [512,640)  L3 [640,672)  L4 [672,688)
__global__ __launch_bounds__(256) void ssim_rest_kernel(
    const float* __restrict__ l1a, const float* __restrict__ l1b,
    const float* __restrict__ l2a, const float* __restrict__ l2b,
    const float* __restrict__ l3a, const float* __restrict__ l3b,
    const float* __restrict__ l4a, const float* __restrict__ l4b,
    float* __restrict__ partials)   // already offset to L1 base
{
    __shared__ float hS[SROWS * HSTRIDE];
    __shared__ float hD[SROWS * HSTRIDE];
    __shared__ float hS2[SROWS * HSTRIDE];
    __shared__ float hD2[SROWS * HSTRIDE];
    __shared__ float red[2][4];

    const int lin = blockIdx.x;
    int level, base;
    if (lin < 512)      { level = 1; base = 0; }
    else if (lin < 640) { level = 2; base = 512; }
    else if (lin < 672) { level = 3; base = 640; }
    else                { level = 4; base = 672; }
    const int Wt[4]   = {256, 128, 64, 32};
    const int ntxl[4] = {2, 1, 0, 0};
    const int ntyl[4] = {3, 2, 1, 0};
    const int idx = level - 1;
    const int W = Wt[idx], H = W;
    const int li = lin - base;
    const int tx = li & ((1 << ntxl[idx]) - 1);
    const int rem = li >> ntxl[idx];
    const int ty = rem & ((1 << ntyl[idx]) - 1);
    const int b = rem >> ntyl[idx];

    const float* ip1; const float* ip2;
    if (level == 1)      { ip1 = l1a; ip2 = l1b; }
    else if (level == 2) { ip1 = l2a; ip2 = l2b; }
    else if (level == 3) { ip1 = l3a; ip2 = l3b; }
    else                 { ip1 = l4a; ip2 = l4b; }
    const float* p1 = ip1 + (size_t)b * H * W;
    const float* p2 = ip2 + (size_t)b * H * W;

    float w[WS];
    gauss_weights(w);

    ssim_tile(p1, p2, H, W, tx * TW, ty * TH, w, hS, hD, hS2, hD2, red,
              partials, lin);
}

// ---------------------------------------------------------------------------
__global__ __launch_bounds__(256) void finalize_kernel(
    const float* __restrict__ partials, float* __restrict__ out)
{
    __shared__ float lvl_s[5], lvl_m[5];
    __shared__ float red[2][4];
    const int nb[5] = {2048, 512, 128, 32, 16};
    const int off[5] = {0, 2048, 2560, 2688, 2720};
    const float npix[5] = {16.f * 512 * 512, 16.f * 256 * 256, 16.f * 128 * 128,
                           16.f * 64 * 64, 16.f * 32 * 32};
    const int tid = threadIdx.x;

    for (int l = 0; l < 5; ++l) {
        float s = 0.f, m = 0.f;
        for (int i = tid; i < nb[l]; i += 256) {
            s += partials[2 * (off[l] + i)];
            m += partials[2 * (off[l] + i) + 1];
        }
#pragma unroll
        for (int o = 32; o > 0; o >>= 1) {
            s += __shfl_down(s, o);
            m += __shfl_down(m, o);
        }
        int wave = tid >> 6, lane = tid & 63;
        if (lane == 0) { red[0][wave] = s; red[1][wave] = m; }
        __syncthreads();
        if (tid == 0) {
            lvl_s[l] = (red[0][0] + red[0][1] + red[0][2] + red[0][3]) / npix[l];
            lvl_m[l] = (red[1][0] + red[1][1] + red[1][2] + red[1][3]) / npix[l];
        }
        __syncthreads();
    }

    if (tid == 0) {
        const float w[5] = {0.0448f, 0.2856f, 0.3001f, 0.2363f, 0.1333f};
        float v = powf(lvl_m[0], w[0]) * powf(lvl_m[1], w[1]) * powf(lvl_m[2], w[2]) *
                  powf(lvl_m[3], w[3]) * powf(lvl_s[4], w[4]);
        v *= 0.5f;
        v = fminf(fmaxf(v, 0.f), 1.f);
        out[0] = v;
    }
}

extern "C" void kernel_launch(void* const* d_in, const int* in_sizes, int n_in,
                              void* d_out, int out_size, void* d_ws, size_t ws_size,
                              hipStream_t stream) {
    const float* img1 = (const float*)d_in[0];
    const float* img2 = (const float*)d_in[1];
    float* out = (float*)d_out;

    const int B = 16;

    float* wsf = (float*)d_ws;
    float* partials = wsf;
    float* p = wsf + 5472;
    float* l1a = p; p += (size_t)B * 256 * 256;
    float* l1b = p; p += (size_t)B * 256 * 256;
    float* l2a = p; p += (size_t)B * 128 * 128;
    float* l2b = p; p += (size_t)B * 128 * 128;
    float* l3a = p; p += (size_t)B * 64 * 64;
    float* l3b = p; p += (size_t)B * 64 * 64;
    float* l4a = p; p += (size_t)B * 32 * 32;
    float* l4b = p; p += (size_t)B * 32 * 32;

    dim3 block(256);

    ssim_l0_pool_kernel<<<dim3(8, 16, B), block, 0, stream>>>(
        img1, img2, l1a, l1b, l2a, l2b, l3a, l3b, l4a, l4b, partials);

    ssim_rest_kernel<<<dim3(688), block, 0, stream>>>(
        l1a, l1b, l2a, l2b, l3a, l3b, l4a, l4b, partials + 2 * 2048);

    finalize_kernel<<<1, block, 0, stream>>>(partials, out);
}